// Round 10
// baseline (110.727 us; speedup 1.0000x reference)
//
#include <hip/hip_runtime.h>
#include <math.h>

#define TPB 256          // threads per block
#define QPT 4            // queries per thread -> 1024 queries per block
#define QSPAN (TPB * QPT)
#define JWIN 128         // shared j-window per block (1 KB LDS, x/y only)
#define BIGV 1e10f
#define EPSV 1e-8f

typedef float f32x2 __attribute__((ext_vector_type(2)));

#if __has_builtin(__builtin_elementwise_fma)
#define VFMA(a, b, c) __builtin_elementwise_fma((a), (b), (c))
#else
static __device__ __forceinline__ f32x2 VFMA(f32x2 a, f32x2 b, f32x2 c) {
    f32x2 r; r.x = fmaf(a.x, b.x, c.x); r.y = fmaf(a.y, b.y, c.y); return r;
}
#endif
#if __has_builtin(__builtin_elementwise_max)
#define VMAX(a, b) __builtin_elementwise_max((a), (b))
#define VMIN(a, b) __builtin_elementwise_min((a), (b))
#else
static __device__ __forceinline__ f32x2 VMAX(f32x2 a, f32x2 b) {
    f32x2 r; r.x = fmaxf(a.x, b.x); r.y = fmaxf(a.y, b.y); return r;
}
static __device__ __forceinline__ f32x2 VMIN(f32x2 a, f32x2 b) {
    f32x2 r; r.x = fminf(a.x, b.x); r.y = fminf(a.y, b.y); return r;
}
#endif

// kernel 1: sq[i] = x*x + y*y (reference rounding) + init packed keys
__global__ void esdf_prep(const float2* __restrict__ pc,
                          float* __restrict__ sq,
                          unsigned long long* __restrict__ key, int n) {
#pragma clang fp contract(off)
    int i = blockIdx.x * blockDim.x + threadIdx.x;
    if (i < n) {
        float2 p = pc[i];
        float xx = p.x * p.x;
        float yy = p.y * p.y;
        sq[i] = xx + yy;
        key[i] = ~0ull;
    }
}

// process one 16-j tile for one query: pk chain -> self-patch -> min-tree ->
// rare rescan recovering exact lowest-j argmin (reference tie semantics).
__device__ __forceinline__ void proc16(const f32x2 (&xp)[8], const f32x2 (&yp)[8],
                                       const f32x2 (&sj)[8],
                                       float xq, float yq, float sq_q,
                                       int j0, int iq, float& best, int& bi) {
#pragma clang fp contract(off)
    const f32x2 xv = {xq, xq}, yv = {yq, yq}, sv = {sq_q, sq_q};
    const f32x2 m2v = {-2.0f, -2.0f}, zv = {0.0f, 0.0f};
    f32x2 d2p[8];
#pragma unroll
    for (int p = 0; p < 8; ++p) {
        f32x2 t   = xp[p] * xv;               // v_pk_mul_f32
        f32x2 dot = VFMA(yp[p], yv, t);       // v_pk_fma_f32 (reference order)
        f32x2 s   = sv + sj[p];               // v_pk_add_f32
        f32x2 d2  = VFMA(m2v, dot, s);        // v_pk_fma_f32
        d2p[p] = VMAX(d2, zv);                // reference clamp
    }
    if (((iq ^ j0) >> 4) == 0) {              // self in this 16-aligned tile
#pragma unroll
        for (int p = 0; p < 8; ++p) {         // mirror reference +eye*BIG
            if (j0 + 2 * p     == iq) d2p[p].x = BIGV;
            if (j0 + 2 * p + 1 == iq) d2p[p].y = BIGV;
        }
    }
    f32x2 m01 = VMIN(d2p[0], d2p[1]);
    f32x2 m23 = VMIN(d2p[2], d2p[3]);
    f32x2 m45 = VMIN(d2p[4], d2p[5]);
    f32x2 m67 = VMIN(d2p[6], d2p[7]);
    f32x2 mA  = VMIN(m01, m23);
    f32x2 mB  = VMIN(m45, m67);
    f32x2 mC  = VMIN(mA, mB);
    float tmin = fminf(mC.x, mC.y);
    if (tmin < best) {                        // rare record update
        best = tmin;
        bool done = false;
#pragma unroll
        for (int k = 0; k < 16; ++k) {        // lowest j achieving tmin
            float v = (k & 1) ? d2p[k >> 1].y : d2p[k >> 1].x;
            if (!done && v == tmin) { bi = j0 + k; done = true; }
        }
    }
}

// kernel 2: QPT=4 queries/thread; block stages one 128-j window (x,y) in LDS;
// sq_j recomputed in regs (bit-identical to esdf_prep) shared by 4 queries.
// Cross-block merge: atomicMin on key=(d2_bits<<32)|j, with safe stale-skip.
__global__ __launch_bounds__(TPB)
void esdf_nn(const float2* __restrict__ pc,
             const float* __restrict__ sq,
             unsigned long long* __restrict__ key, int n) {
#pragma clang fp contract(off)
    const int tid    = threadIdx.x;
    const int jparts = n / JWIN;                  // 128
    const int qblk   = blockIdx.x / jparts;       // 16 query blocks
    const int jpart  = blockIdx.x % jparts;
    const int qbase  = qblk * QSPAN;
    const int jbase  = jpart * JWIN;

    __shared__ float sXl[JWIN];
    __shared__ float sYl[JWIN];
    if (tid < JWIN) {
        float2 p = pc[jbase + tid];
        sXl[tid] = p.x;
        sYl[tid] = p.y;
    }

    int   iq[QPT];
    float xq[QPT], yq[QPT], sqq[QPT];
#pragma unroll
    for (int m = 0; m < QPT; ++m) {
        iq[m] = qbase + m * TPB + tid;
        float2 p = pc[iq[m]];
        xq[m] = p.x; yq[m] = p.y;
        sqq[m] = sq[iq[m]];
    }
    __syncthreads();

    float best[QPT];
    int   bi[QPT];
#pragma unroll
    for (int m = 0; m < QPT; ++m) { best[m] = BIGV; bi[m] = 0; }

    for (int jt = 0; jt < JWIN; jt += 16) {
        const int j0 = jbase + jt;
        float4 xA = *(const float4*)&sXl[jt];
        float4 xB = *(const float4*)&sXl[jt + 4];
        float4 xC = *(const float4*)&sXl[jt + 8];
        float4 xD = *(const float4*)&sXl[jt + 12];
        float4 yA = *(const float4*)&sYl[jt];
        float4 yB = *(const float4*)&sYl[jt + 4];
        float4 yC = *(const float4*)&sYl[jt + 8];
        float4 yD = *(const float4*)&sYl[jt + 12];
        f32x2 xp[8] = {{xA.x, xA.y}, {xA.z, xA.w}, {xB.x, xB.y}, {xB.z, xB.w},
                       {xC.x, xC.y}, {xC.z, xC.w}, {xD.x, xD.y}, {xD.z, xD.w}};
        f32x2 yp[8] = {{yA.x, yA.y}, {yA.z, yA.w}, {yB.x, yB.y}, {yB.z, yB.w},
                       {yC.x, yC.y}, {yC.z, yC.w}, {yD.x, yD.y}, {yD.z, yD.w}};
        // sq_j recomputed exactly as esdf_prep: rnd(x*x) + rnd(y*y)
        f32x2 sj[8];
#pragma unroll
        for (int p = 0; p < 8; ++p) {
            f32x2 xx = xp[p] * xp[p];
            f32x2 yy = yp[p] * yp[p];
            sj[p] = xx + yy;
        }
#pragma unroll
        for (int m = 0; m < QPT; ++m)
            proc16(xp, yp, sj, xq[m], yq[m], sqq[m], j0, iq[m], best[m], bi[m]);
    }

    // pack (d2,j) -> u64 key; lexicographic min == numpy argmin w/ low-j ties
#pragma unroll
    for (int m = 0; m < QPT; ++m) {
        unsigned long long kk =
            ((unsigned long long)__float_as_uint(best[m]) << 32) | (unsigned)bi[m];
        // stale-skip: key[] only decreases; any read value >= final value,
        // so skipping when kk >= read is always safe.
        unsigned long long cur = *(const volatile unsigned long long*)&key[iq[m]];
        if (kk < cur) atomicMin(&key[iq[m]], kk);
    }
}

// kernel 3: unpack key + epilogue
__global__ void esdf_finalize(const float2* __restrict__ pc,
                              const unsigned long long* __restrict__ key,
                              float* __restrict__ out, int n) {
#pragma clang fp contract(off)
    int q = blockIdx.x * blockDim.x + threadIdx.x;
    if (q >= n) return;
    unsigned long long k = key[q];
    int   ix = (int)(k & 0xffffffffull);
    float b  = __uint_as_float((unsigned)(k >> 32));
    float esdf = sqrtf(b);
    float2 pn = pc[ix];
    float2 pq = pc[q];
    float dx = pq.x - pn.x;
    float dy = pq.y - pn.y;
    float a  = dx * dx;
    float c2 = dy * dy;
    float nrm = sqrtf(a + c2);
    float inv = nrm + EPSV;
    float gx = dx / inv;
    float gy = dy / inv;
    // out = mu(4,N) then lam(3,N), flat
    out[0 * n + q] = gx;
    out[1 * n + q] = -gx;
    out[2 * n + q] = gy;
    out[3 * n + q] = -gy;
    out[4 * n + q] = gx;
    out[5 * n + q] = gy;
    out[6 * n + q] = esdf / 10.0f;
}

extern "C" void kernel_launch(void* const* d_in, const int* in_sizes, int n_in,
                              void* d_out, int out_size, void* d_ws, size_t ws_size,
                              hipStream_t stream) {
    const float2* pc = (const float2*)d_in[0];
    float* out = (float*)d_out;
    const int n = in_sizes[0] / 2;               // 16384

    // ws layout: sq[n] f32 (64KB) | key[n] u64 (128KB)
    float* sq = (float*)d_ws;
    unsigned long long* key = (unsigned long long*)(sq + n);

    const int jparts = n / JWIN;                 // 128
    const int qblks  = n / QSPAN;                // 16

    esdf_prep<<<(n + 255) / 256, 256, 0, stream>>>(pc, sq, key, n);
    esdf_nn<<<qblks * jparts, TPB, 0, stream>>>(pc, sq, key, n);
    esdf_finalize<<<(n + 255) / 256, 256, 0, stream>>>(pc, key, out, n);
}

// Round 11
// 48.359 us; speedup vs baseline: 2.2897x; 2.2897x over previous
//
#include <hip/hip_runtime.h>
#include <math.h>

#define TPB 256          // threads per block, 1 query per thread
#define JWIN 512         // shared j-window per block, staged in LDS SoA (6 KB)
#define BIGV 1e10f
#define EPSV 1e-8f

// kernel 1: sq[i] = x*x + y*y (reference rounding) + init packed keys
__global__ void esdf_prep(const float2* __restrict__ pc,
                          float* __restrict__ sq,
                          unsigned long long* __restrict__ key, int n) {
#pragma clang fp contract(off)
    int i = blockIdx.x * blockDim.x + threadIdx.x;
    if (i < n) {
        float2 p = pc[i];
        float xx = p.x * p.x;
        float yy = p.y * p.y;
        sq[i] = xx + yy;
        key[i] = ~0ull;
    }
}

// kernel 2: R5 skeleton + min-tree bookkeeping. Per 8-j tile: 40 exact arith
// + fmin tree (v_min3) + 2-op running (best, best_tile) update. NO per-pair
// index tracking; exact argmin recovered in finalize from the winning tile.
// Diagonal: BIG-patch only in self-window blocks / self-range tiles.
// Cross-block merge: atomicMin on key=(best_bits<<32)|tile (lexicographic ==
// first-tile-achieving-min == numpy first-index semantics).
__global__ __launch_bounds__(TPB)
void esdf_nn(const float2* __restrict__ pc,
             const float* __restrict__ sq,
             unsigned long long* __restrict__ key, int n) {
#pragma clang fp contract(off)
    const int tid    = threadIdx.x;
    const int jparts = n / JWIN;                  // 32
    const int qblk   = blockIdx.x / jparts;       // 64 query blocks
    const int jpart  = blockIdx.x % jparts;
    const int qbase  = qblk * TPB;
    const int jbase  = jpart * JWIN;
    // self-point lies in this window iff the 512-aligned hull of qbase == jbase
    const bool selfwin = ((qbase & ~(JWIN - 1)) == jbase);
    // this thread's wave covers queries [qw, qw+64)
    const int qw = qbase + (tid & 192);

    // --- stage j-window into LDS SoA (coalesced vector-ish loads) ---
    __shared__ float sXl[JWIN];
    __shared__ float sYl[JWIN];
    __shared__ float sSql[JWIN];
#pragma unroll
    for (int h = 0; h < JWIN / TPB; ++h) {
        int t = h * TPB + tid;
        float2 p = pc[jbase + t];
        sXl[t] = p.x;
        sYl[t] = p.y;
        sSql[t] = sq[jbase + t];
    }

    const int q = qbase + tid;
    float2 pq = pc[q];
    const float xq = pq.x, yq = pq.y, sqq = sq[q];
    __syncthreads();

    float best  = BIGV;
    int   btile = 0;

    for (int jt = 0; jt < JWIN; jt += 8) {
        const int j0 = jbase + jt;                // block-uniform
        float4 xA = *(const float4*)&sXl[jt];     // 6x ds_read_b128
        float4 xB = *(const float4*)&sXl[jt + 4];
        float4 yA = *(const float4*)&sYl[jt];
        float4 yB = *(const float4*)&sYl[jt + 4];
        float4 sA = *(const float4*)&sSql[jt];
        float4 sB = *(const float4*)&sSql[jt + 4];
        float xs[8] = {xA.x, xA.y, xA.z, xA.w, xB.x, xB.y, xB.z, xB.w};
        float ys[8] = {yA.x, yA.y, yA.z, yA.w, yB.x, yB.y, yB.z, yB.w};
        float ss[8] = {sA.x, sA.y, sA.z, sA.w, sB.x, sB.y, sB.z, sB.w};

        float d[8];
#pragma unroll
        for (int k = 0; k < 8; ++k) {             // exact reference rounding
            float dot = fmaf(ys[k], yq, xs[k] * xq);   // BLAS fma order
            float s   = sqq + ss[k];
            float v   = fmaf(-2.0f, dot, s);
            d[k] = fmaxf(v, 0.0f);
        }

        // diagonal patch (mirror reference +eye*BIG); wave-uniform guards keep
        // this off the hot path for 31/32 blocks and 56/64 tiles of the rest
        if (selfwin && ((j0 & ~63) == qw)) {
#pragma unroll
            for (int k = 0; k < 8; ++k)
                if (j0 + k == q) d[k] = BIGV;
        }

        // fmin tree (fuses to v_min3_f32) -> tile min VALUE only
        float m01 = fminf(fminf(d[0], d[1]), d[2]);
        float m23 = fminf(fminf(d[3], d[4]), d[5]);
        float m45 = fminf(d[6], d[7]);
        float tmin = fminf(fminf(m01, m23), m45);

        // running (best, first-tile-achieving-best) update; strict < keeps
        // the EARLIEST tile on ties
        const int tileId = j0 >> 3;               // uniform (SGPR)
        bool lt = tmin < best;
        best  = fminf(best, tmin);
        btile = lt ? tileId : btile;              // v_cndmask
    }

    // key = (best_bits<<32)|btile; lexicographic min across blocks picks the
    // smallest d2, then earliest tile. best>=0 so float order == bits order.
    unsigned long long kk =
        ((unsigned long long)__float_as_uint(best) << 32) | (unsigned)btile;
    // stale-skip: key[] only decreases, so skipping when kk >= read is safe
    unsigned long long cur = *(const volatile unsigned long long*)&key[q];
    if (kk < cur) atomicMin(&key[q], kk);
}

// kernel 3: recover exact argmin from the winning tile + epilogue
__global__ void esdf_finalize(const float2* __restrict__ pc,
                              const float* __restrict__ sq,
                              const unsigned long long* __restrict__ key,
                              float* __restrict__ out, int n) {
#pragma clang fp contract(off)
    int q = blockIdx.x * blockDim.x + threadIdx.x;
    if (q >= n) return;
    unsigned long long k = key[q];
    float best = __uint_as_float((unsigned)(k >> 32));
    int   j0   = ((int)(k & 0xffffffffull)) << 3;

    float2 pq = pc[q];
    const float xq = pq.x, yq = pq.y, sqq = sq[q];

    int ix = j0;                                  // safe fallback
    bool found = false;
#pragma unroll
    for (int kk = 0; kk < 8; ++kk) {              // first j with d2 == best
        int j = j0 + kk;
        float2 pj = pc[j];
        float dot = fmaf(pj.y, yq, pj.x * xq);    // exact recompute, same bits
        float s   = sqq + sq[j];
        float v   = fmaf(-2.0f, dot, s);
        v = fmaxf(v, 0.0f);
        if (!found && j != q && v == best) { ix = j; found = true; }
    }

    float esdf = sqrtf(best);
    float2 pn = pc[ix];
    float dx = xq - pn.x;
    float dy = yq - pn.y;
    float a  = dx * dx;
    float c2 = dy * dy;
    float nrm = sqrtf(a + c2);
    float inv = nrm + EPSV;
    float gx = dx / inv;
    float gy = dy / inv;
    // out = mu(4,N) then lam(3,N), flat
    out[0 * n + q] = gx;
    out[1 * n + q] = -gx;
    out[2 * n + q] = gy;
    out[3 * n + q] = -gy;
    out[4 * n + q] = gx;
    out[5 * n + q] = gy;
    out[6 * n + q] = esdf / 10.0f;
}

extern "C" void kernel_launch(void* const* d_in, const int* in_sizes, int n_in,
                              void* d_out, int out_size, void* d_ws, size_t ws_size,
                              hipStream_t stream) {
    const float2* pc = (const float2*)d_in[0];
    float* out = (float*)d_out;
    const int n = in_sizes[0] / 2;               // 16384

    // ws layout: sq[n] f32 (64KB) | key[n] u64 (128KB)
    float* sq = (float*)d_ws;
    unsigned long long* key = (unsigned long long*)(sq + n);

    const int jparts = n / JWIN;                 // 32
    const int qblks  = n / TPB;                  // 64

    esdf_prep<<<(n + 255) / 256, 256, 0, stream>>>(pc, sq, key, n);
    esdf_nn<<<qblks * jparts, TPB, 0, stream>>>(pc, sq, key, n);
    esdf_finalize<<<(n + 255) / 256, 256, 0, stream>>>(pc, sq, key, out, n);
}